// Round 15
// baseline (433.264 us; speedup 1.0000x reference)
//
#include <hip/hip_runtime.h>
#include <hip/hip_fp16.h>
#include <math.h>

// ---------------------------------------------------------------------------
// SovereignLeviathanV2  round 15 = round 12 k_ffn (unroll 8, proven 147us)
// + wave-rotated K-loops: GEMM1 ks=(ks0+w*4)&31, GEMM2 fs=(fs0+w*2)&15.
// Co-resident waves (2/SIMD) de-phase within each barrier phase -> LDS-read,
// MFMA and VALU bursts of the two waves interleave instead of colliding.
// Pure fp32 accumulation reorder (exact same rank-16 updates).
// Everything else byte-identical to the passing round-12/14 kernel.
// ---------------------------------------------------------------------------

#define PI_F 3.14159265358979323846f
#define HARM_F 1.04719755119659774615f
#define INV_HARM_F 0.95492965855137201461f
#define TOL_F 0.15f

typedef float f32x16 __attribute__((ext_vector_type(16)));
typedef __bf16 bf16x8 __attribute__((ext_vector_type(8)));
typedef unsigned int u32x4 __attribute__((ext_vector_type(4)));
typedef unsigned int u32x2 __attribute__((ext_vector_type(2)));

__device__ __forceinline__ float bflo(unsigned u) { return __uint_as_float(u << 16); }
__device__ __forceinline__ float bfhi(unsigned u) { return __uint_as_float(u & 0xFFFF0000u); }
__device__ __forceinline__ unsigned short f2bf(float x) {
  unsigned u = __float_as_uint(x);
  unsigned r = (u + 0x7FFFu + ((u >> 16) & 1u)) >> 16;
  return (unsigned short)r;
}
__device__ __forceinline__ bf16x8 ld_frag(const void* p) {
  u32x4 v = *(const u32x4*)p;
  return __builtin_bit_cast(bf16x8, v);
}
__device__ __forceinline__ float tanh_fast(float z) {
  float zc = fminf(10.f, fmaxf(-10.f, z));
  float e2 = __expf(zc + zc);
  return (e2 - 1.f) / (e2 + 1.f);
}
__device__ __forceinline__ float sigmoid_fast(float z) {
  return 1.f / (1.f + __expf(-z));
}
__device__ __forceinline__ float gelu_tanh(float x) {
  float x3 = x * x * x;
  float t = 0.79788456080286535588f * (x + 0.044715f * x3);
  return 0.5f * x * (1.f + tanh_fast(t));
}
__device__ __forceinline__ void sincos_poly(float a, float* sn, float* cs) {
  float q = rintf(a * 0.63661977236758134f);
  int iq = (int)q;
  float t = fmaf(-q, 1.57079637050628662f, a);
  t = fmaf(q, 4.37113883e-8f, t);
  float t2 = t * t;
  float sp = t * fmaf(t2, fmaf(t2, fmaf(t2, -1.9515296e-4f, 8.3321609e-3f),
                               -1.6666654e-1f), 1.f);
  float cp = fmaf(t2 * t2,
                  fmaf(t2, fmaf(t2, 2.4433158e-5f, -1.3887316e-3f), 4.1666646e-2f),
                  fmaf(t2, -0.5f, 1.f));
  int m = iq & 3;
  bool swap = (m & 1) != 0;
  float ss = swap ? cp : sp;
  float cc = swap ? sp : cp;
  *sn = (m & 2) ? -ss : ss;
  *cs = ((m + 1) & 2) ? -cc : cc;
}

// K1 v2: frag-packed Xhi/Xlo
__global__ void k_embed2(const int* __restrict__ seq, const float* __restrict__ emb,
                         unsigned short* __restrict__ XhiP,
                         unsigned short* __restrict__ XloP) {
  int gid = blockIdx.x * 256 + threadIdx.x;
  int ent = gid >> 6, l = gid & 63;
  int tb = ent >> 5, ks = ent & 31;
  int tok = tb * 32 + (l & 31);
  int k0 = ks * 16 + (l >> 5) * 8;
  const float* src = emb + (size_t)seq[tok] * 512 + k0;
  float4 v0 = *(const float4*)src;
  float4 v1 = *(const float4*)(src + 4);
  float vv[8] = {v0.x, v0.y, v0.z, v0.w, v1.x, v1.y, v1.z, v1.w};
  unsigned h[8], lo[8];
#pragma unroll
  for (int j = 0; j < 8; ++j) {
    h[j] = f2bf(vv[j]);
    lo[j] = f2bf(vv[j] - bflo(h[j]));
  }
  u32x4 H, L;
  H.x = h[0] | (h[1] << 16);  H.y = h[2] | (h[3] << 16);
  H.z = h[4] | (h[5] << 16);  H.w = h[6] | (h[7] << 16);
  L.x = lo[0] | (lo[1] << 16); L.y = lo[2] | (lo[3] << 16);
  L.z = lo[4] | (lo[5] << 16); L.w = lo[6] | (lo[7] << 16);
  *(u32x4*)(XhiP + (size_t)ent * 512 + l * 8) = H;
  *(u32x4*)(XloP + (size_t)ent * 512 + l * 8) = L;
}

// Generic B-operand frag pack
__global__ __launch_bounds__(256) void k_pack_b(const float* __restrict__ src, int ld,
                                                size_t srcE, unsigned short* __restrict__ dst,
                                                size_t dstE, int fragKtot) {
  __shared__ float Ls[512 * 33];
  int nb = blockIdx.x, kseg = blockIdx.y, e = blockIdx.z;
  const float* s = src + (size_t)e * srcE + (size_t)kseg * 512 * ld + nb * 32;
  unsigned short* d = dst + (size_t)e * dstE + ((size_t)(nb * fragKtot + kseg * 32)) * 512;
  int tid = threadIdx.x;
#pragma unroll
  for (int q = 0; q < 16; ++q) {
    int i = tid + q * 256;
    int row = i >> 3, c4 = i & 7;
    float4 v = *(const float4*)(s + (size_t)row * ld + c4 * 4);
    Ls[row * 33 + c4 * 4 + 0] = v.x;
    Ls[row * 33 + c4 * 4 + 1] = v.y;
    Ls[row * 33 + c4 * 4 + 2] = v.z;
    Ls[row * 33 + c4 * 4 + 3] = v.w;
  }
  __syncthreads();
#pragma unroll
  for (int q = 0; q < 8; ++q) {
    int i = tid + q * 256;
    int ks = i >> 6, l = i & 63;
    int col = l & 31, kb = (l >> 5) * 8 + ks * 16;
    u32x4 o;
    o.x = (unsigned)f2bf(Ls[(kb + 0) * 33 + col]) | ((unsigned)f2bf(Ls[(kb + 1) * 33 + col]) << 16);
    o.y = (unsigned)f2bf(Ls[(kb + 2) * 33 + col]) | ((unsigned)f2bf(Ls[(kb + 3) * 33 + col]) << 16);
    o.z = (unsigned)f2bf(Ls[(kb + 4) * 33 + col]) | ((unsigned)f2bf(Ls[(kb + 5) * 33 + col]) << 16);
    o.w = (unsigned)f2bf(Ls[(kb + 6) * 33 + col]) | ((unsigned)f2bf(Ls[(kb + 7) * 33 + col]) << 16);
    *(u32x4*)(d + (size_t)ks * 512 + l * 8) = o;
  }
}

// K2 v5: bf16x3 MFMA phi+amp GEMM
__global__ __launch_bounds__(256, 3) void k_phi(
    const unsigned short* __restrict__ XhiP, const unsigned short* __restrict__ XloP,
    const float* __restrict__ phiW, const float* __restrict__ phiB,
    const float* __restrict__ ampW, const float* __restrict__ ampB,
    float* __restrict__ cosO, float* __restrict__ sinO, float* __restrict__ sigO) {
  __shared__ __align__(16) char wlds[2][8][1024];
  int tid = threadIdx.x;
  int w = tid >> 6, l = tid & 63;
  int l31 = l & 31, hi = l >> 5;
  int by = blockIdx.y;
  const float* Bsrc = (by < 4) ? phiW : ampW;
  const float* bias = (by < 4) ? phiB : ampB;
  int cb = (by & 3) * 128;

#define STAGE_W(KS, BUF)                                                        \
  {                                                                             \
    const float* wsrc = Bsrc + (size_t)((KS)*16 + hi * 8) * 512 + cb + w * 32 + l31; \
    float v0 = wsrc[0],    v1 = wsrc[512],  v2 = wsrc[1024], v3 = wsrc[1536];   \
    float v4 = wsrc[2048], v5 = wsrc[2560], v6 = wsrc[3072], v7 = wsrc[3584];   \
    unsigned h0 = f2bf(v0), h1 = f2bf(v1), h2 = f2bf(v2), h3 = f2bf(v3);        \
    unsigned h4 = f2bf(v4), h5 = f2bf(v5), h6 = f2bf(v6), h7 = f2bf(v7);        \
    u32x4 H, L;                                                                 \
    H.x = h0 | (h1 << 16); H.y = h2 | (h3 << 16);                               \
    H.z = h4 | (h5 << 16); H.w = h6 | (h7 << 16);                               \
    L.x = (unsigned)f2bf(v0 - bflo(h0)) | ((unsigned)f2bf(v1 - bflo(h1)) << 16); \
    L.y = (unsigned)f2bf(v2 - bflo(h2)) | ((unsigned)f2bf(v3 - bflo(h3)) << 16); \
    L.z = (unsigned)f2bf(v4 - bflo(h4)) | ((unsigned)f2bf(v5 - bflo(h5)) << 16); \
    L.w = (unsigned)f2bf(v6 - bflo(h6)) | ((unsigned)f2bf(v7 - bflo(h7)) << 16); \
    *(u32x4*)(&wlds[BUF][w * 2 + 0][l * 16]) = H;                               \
    *(u32x4*)(&wlds[BUF][w * 2 + 1][l * 16]) = L;                               \
  }

  int tb = blockIdx.x * 4 + w;
  const unsigned short* xh_base = XhiP + ((size_t)tb * 32) * 512 + l * 8;
  const unsigned short* xl_base = XloP + ((size_t)tb * 32) * 512 + l * 8;
  f32x16 a0, a1, a2, a3;
#pragma unroll
  for (int i = 0; i < 16; ++i) { a0[i] = 0.f; a1[i] = 0.f; a2[i] = 0.f; a3[i] = 0.f; }

  STAGE_W(0, 0);
  for (int ks = 0; ks < 32; ++ks) {
    __syncthreads();
    if (ks + 1 < 32) {
      if (((ks + 1) & 1) == 0) STAGE_W(ks + 1, 0) else STAGE_W(ks + 1, 1)
    }
    bf16x8 xh = *(const bf16x8*)(xh_base + (size_t)ks * 512);
    bf16x8 xl = *(const bf16x8*)(xl_base + (size_t)ks * 512);
    const char (*wb)[1024] = wlds[ks & 1];
    bf16x8 wh0 = ld_frag(&wb[0][l * 16]), wl0 = ld_frag(&wb[1][l * 16]);
    bf16x8 wh1 = ld_frag(&wb[2][l * 16]), wl1 = ld_frag(&wb[3][l * 16]);
    bf16x8 wh2 = ld_frag(&wb[4][l * 16]), wl2 = ld_frag(&wb[5][l * 16]);
    bf16x8 wh3 = ld_frag(&wb[6][l * 16]), wl3 = ld_frag(&wb[7][l * 16]);
    a0 = __builtin_amdgcn_mfma_f32_32x32x16_bf16(xh, wh0, a0, 0, 0, 0);
    a1 = __builtin_amdgcn_mfma_f32_32x32x16_bf16(xh, wh1, a1, 0, 0, 0);
    a2 = __builtin_amdgcn_mfma_f32_32x32x16_bf16(xh, wh2, a2, 0, 0, 0);
    a3 = __builtin_amdgcn_mfma_f32_32x32x16_bf16(xh, wh3, a3, 0, 0, 0);
    a0 = __builtin_amdgcn_mfma_f32_32x32x16_bf16(xl, wh0, a0, 0, 0, 0);
    a1 = __builtin_amdgcn_mfma_f32_32x32x16_bf16(xl, wh1, a1, 0, 0, 0);
    a2 = __builtin_amdgcn_mfma_f32_32x32x16_bf16(xl, wh2, a2, 0, 0, 0);
    a3 = __builtin_amdgcn_mfma_f32_32x32x16_bf16(xl, wh3, a3, 0, 0, 0);
    a0 = __builtin_amdgcn_mfma_f32_32x32x16_bf16(xh, wl0, a0, 0, 0, 0);
    a1 = __builtin_amdgcn_mfma_f32_32x32x16_bf16(xh, wl1, a1, 0, 0, 0);
    a2 = __builtin_amdgcn_mfma_f32_32x32x16_bf16(xh, wl2, a2, 0, 0, 0);
    a3 = __builtin_amdgcn_mfma_f32_32x32x16_bf16(xh, wl3, a3, 0, 0, 0);
  }

  int tokBase = blockIdx.x * 128 + w * 32;
#define PHI_EPI(ACC, NB)                                                        \
  {                                                                             \
    int c = cb + (NB)*32 + l31;                                                 \
    float bs = bias[c];                                                         \
    if (by < 4) {                                                               \
      _Pragma("unroll") for (int r = 0; r < 16; ++r) {                          \
        int tok = tokBase + (r & 3) + 8 * (r >> 2) + 4 * hi;                    \
        float z = ACC[r] + bs;                                                  \
        float a = tanh_fast(z) * PI_F;                                          \
        float nr = rintf(a * INV_HARM_F) * HARM_F;                              \
        if (fabsf(a - nr) < TOL_F) a = nr;                                      \
        float sn, cs;                                                           \
        sincos_poly(a, &sn, &cs);                                               \
        cosO[(size_t)tok * 512 + c] = cs;                                       \
        sinO[(size_t)tok * 512 + c] = sn;                                       \
      }                                                                         \
    } else {                                                                    \
      _Pragma("unroll") for (int r = 0; r < 16; ++r) {                          \
        int tok = tokBase + (r & 3) + 8 * (r >> 2) + 4 * hi;                    \
        sigO[(size_t)tok * 512 + c] = sigmoid_fast(ACC[r] + bs);                \
      }                                                                         \
    }                                                                           \
  }
  PHI_EPI(a0, 0)
  PHI_EPI(a1, 1)
  PHI_EPI(a2, 2)
  PHI_EPI(a3, 3)
}

// K3 v3: producer-consumer toroidal scan
__global__ __launch_bounds__(256, 1) void k_scan(const float* __restrict__ cosb,
                                                 const float* __restrict__ sinb,
                                                 const float* __restrict__ sigb,
                                                 float* __restrict__ xmoe,
                                                 float* __restrict__ nstate) {
  __shared__ float lds[2][3][64 * 64];
  int tid = threadIdx.x;
  int wv = tid >> 6, l = tid & 63;
  int b = blockIdx.x >> 3;
  int c0 = (blockIdx.x & 7) << 6;
  size_t base = ((size_t)b * 2048) * 512 + c0;

#define SCAN_STAGE(SRC, K, BUF)                                                \
  {                                                                            \
    float4 tmp[16];                                                            \
    size_t sb = base + ((size_t)(K) * 64 + tq) * 512 + cq * 4;                 \
    _Pragma("unroll") for (int t4 = 0; t4 < 16; ++t4)                          \
      tmp[t4] = *(const float4*)((SRC) + sb + (size_t)t4 * 4 * 512);           \
    _Pragma("unroll") for (int t4 = 0; t4 < 16; ++t4)                          \
      *(float4*)(&lds[BUF][wv - 1][(t4 * 4 + tq) * 64 + cq * 4]) = tmp[t4];    \
  }

  if (wv > 0) {
    const float* src = (wv == 1) ? cosb : (wv == 2) ? sinb : sigb;
    int tq = l >> 4, cq = l & 15;
    SCAN_STAGE(src, 0, 0);
    __syncthreads();
    for (int k = 0; k < 32; ++k) {
      if (k + 1 < 32) {
        if (((k + 1) & 1) == 0) SCAN_STAGE(src, k + 1, 0)
        else                    SCAN_STAGE(src, k + 1, 1)
      }
      __syncthreads();
    }
  } else {
    __syncthreads();
    float state = 0.f;
    for (int k = 0; k < 32; ++k) {
      const float* bufC = &lds[k & 1][0][0];
      const float* bufS = &lds[k & 1][1][0];
      const float* bufG = &lds[k & 1][2][0];
      size_t outb = base + (size_t)k * 64 * 512 + l;
#pragma unroll
      for (int tt = 0; tt < 64; ++tt) {
        float pc = bufC[tt * 64 + l];
        float ps = bufS[tt * 64 + l];
        float pg = bufG[tt * 64 + l];
        float st = fmaf(pc + ps, state, -ps);
        st = fminf(1.f, fmaxf(-1.f, st));
        state = st;
        xmoe[outb + (size_t)tt * 512] = pg * st;
      }
      __syncthreads();
    }
    nstate[(size_t)b * 512 + c0 + l] = state;
  }
}

// K4: gate logits + softmax + top2
__global__ __launch_bounds__(256) void k_gate(const float* __restrict__ xmoe,
                                              const float* __restrict__ gw_g,
                                              const float* __restrict__ gb,
                                              int* __restrict__ e01p,
                                              unsigned* __restrict__ w01p) {
  __shared__ float gw[4096];
  int tid = threadIdx.x;
  for (int i = tid; i < 4096; i += 256) gw[i] = gw_g[i];
  __syncthreads();
  int tok = blockIdx.x * 32 + (tid >> 3);
  int e = tid & 7;
  float acc = gb[e];
  const float4* xr = (const float4*)(xmoe + (size_t)tok * 512);
  for (int k4 = 0; k4 < 128; ++k4) {
    float4 x = xr[k4];
    acc += x.x * gw[(k4 * 4 + 0) * 8 + e];
    acc += x.y * gw[(k4 * 4 + 1) * 8 + e];
    acc += x.z * gw[(k4 * 4 + 2) * 8 + e];
    acc += x.w * gw[(k4 * 4 + 3) * 8 + e];
  }
  float m = acc;
  m = fmaxf(m, __shfl_xor(m, 1));
  m = fmaxf(m, __shfl_xor(m, 2));
  m = fmaxf(m, __shfl_xor(m, 4));
  float p = expf(acc - m);
  float ss = p;
  ss += __shfl_xor(ss, 1); ss += __shfl_xor(ss, 2); ss += __shfl_xor(ss, 4);
  p /= ss;
  float v1 = p; int i1 = e;
  {
    float ov; int oi;
    ov = __shfl_xor(v1, 1); oi = __shfl_xor(i1, 1);
    if (ov > v1 || (ov == v1 && oi < i1)) { v1 = ov; i1 = oi; }
    ov = __shfl_xor(v1, 2); oi = __shfl_xor(i1, 2);
    if (ov > v1 || (ov == v1 && oi < i1)) { v1 = ov; i1 = oi; }
    ov = __shfl_xor(v1, 4); oi = __shfl_xor(i1, 4);
    if (ov > v1 || (ov == v1 && oi < i1)) { v1 = ov; i1 = oi; }
  }
  float v2 = (e == i1) ? -1.f : p; int i2 = e;
  {
    float ov; int oi;
    ov = __shfl_xor(v2, 1); oi = __shfl_xor(i2, 1);
    if (ov > v2 || (ov == v2 && oi < i2)) { v2 = ov; i2 = oi; }
    ov = __shfl_xor(v2, 2); oi = __shfl_xor(i2, 2);
    if (ov > v2 || (ov == v2 && oi < i2)) { v2 = ov; i2 = oi; }
    ov = __shfl_xor(v2, 4); oi = __shfl_xor(i2, 4);
    if (ov > v2 || (ov == v2 && oi < i2)) { v2 = ov; i2 = oi; }
  }
  if (e == 0) {
    float s2 = v1 + v2;
    __half h1 = __float2half(v1 / s2), h2 = __float2half(v2 / s2);
    e01p[tok] = i1 | (i2 << 8);
    w01p[tok] = (unsigned)__half_as_ushort(h1) | ((unsigned)__half_as_ushort(h2) << 16);
  }
}

// K6: counts -> eoff -> scatter -> tmap (96-tok tiles)
__global__ void k_build(const int* __restrict__ e01p, const unsigned* __restrict__ w01p,
                        int* __restrict__ list, float* __restrict__ wlist,
                        int* __restrict__ counts, int* __restrict__ eoff,
                        int* __restrict__ tokpos, int* __restrict__ tmap) {
  __shared__ int cnt[8], cur[8];
  int tid = threadIdx.x, lane = tid & 63;
  if (tid < 8) cnt[tid] = 0;
  __syncthreads();
  for (int i = tid; i < 16384; i += 256) {
    int tok = i >> 1, j = i & 1;
    int ee = (e01p[tok] >> (8 * j)) & 255;
#pragma unroll
    for (int x = 0; x < 8; ++x) {
      unsigned long long m = __ballot(ee == x);
      if (m != 0ull && lane == (__ffsll((long long)m) - 1)) atomicAdd(&cnt[x], __popcll(m));
    }
  }
  __syncthreads();
  if (tid == 0) {
    int s = 0;
#pragma unroll
    for (int x = 0; x < 8; ++x) {
      cur[x] = s; eoff[x] = s; counts[x] = cnt[x]; s += cnt[x];
    }
  }
  __syncthreads();
  for (int i = tid; i < 272; i += 256) tmap[i] = -1;
  __syncthreads();
  if (tid == 0) {
    int ntiles = 0, tstart[8];
#pragma unroll
    for (int e = 0; e < 8; ++e) { tstart[e] = ntiles; ntiles += (cnt[e] + 95) / 96; }
    int q = ntiles >> 3, r = ntiles & 7;
    for (int e = 0; e < 8; ++e) {
      int nt = (cnt[e] + 95) / 96;
      for (int t = 0; t < nt; ++t) {
        int k = tstart[e] + t;
        int c, o;
        if (k < r * (q + 1)) { c = k / (q + 1); o = k - c * (q + 1); }
        else { int k2 = k - r * (q + 1); c = r + k2 / q; o = k2 - (k2 / q) * q; }
        tmap[8 * o + c] = (e << 16) | t;
      }
    }
  }
  __syncthreads();
  for (int i = tid; i < 16384; i += 256) {
    int tok = i >> 1, j = i & 1;
    int ee = (e01p[tok] >> (8 * j)) & 255;
    unsigned wp = w01p[tok];
    unsigned short us = (unsigned short)(j ? (wp >> 16) : (wp & 0xFFFFu));
    float w = __half2float(__ushort_as_half(us));
    int pos = 0;
#pragma unroll
    for (int x = 0; x < 8; ++x) {
      unsigned long long m = __ballot(ee == x);
      if (m == 0ull) continue;
      int leader = __ffsll((long long)m) - 1;
      int bb = 0;
      if (lane == leader) bb = atomicAdd(&cur[x], __popcll(m));
      bb = __shfl(bb, leader);
      if (ee == x) pos = bb + __popcll(m & ((1ull << lane) - 1ull));
    }
    list[pos] = tok;
    wlist[pos] = w;
    tokpos[i] = pos;
  }
}

// ---------------------------------------------------------------------------
// K7 v4.2: fused MoE FFN, 96-token tiles, 512 thr / 8 waves, wave-rotated
// K-loops (co-resident waves de-phased within each barrier phase).
// ---------------------------------------------------------------------------
#define HS_OFF 98304

__global__ __launch_bounds__(512, 2) void k_ffn(
    const float* __restrict__ xmoe, const int* __restrict__ list,
    const float* __restrict__ wlist, const int* __restrict__ counts,
    const int* __restrict__ eoff, const int* __restrict__ tmap,
    const unsigned short* __restrict__ W1Pk, const float* __restrict__ b1g,
    const unsigned short* __restrict__ W2Pk, const float* __restrict__ b2g,
    unsigned short* __restrict__ Yb) {
  int mp = tmap[blockIdx.x];
  if (mp < 0) return;
  int e = mp >> 16, tile = mp & 0xFFFF;
  int cnt = counts[e];
  int base = eoff[e] + tile * 96;
  int valid = cnt - tile * 96;
  if (valid > 96) valid = 96;
  __shared__ __align__(16) char smem[147456];  // Xs 96KB | Hs 48KB
  __shared__ int toks[96];
  __shared__ float wts[96];
  int tid = threadIdx.x;
  int w = tid >> 6, l = tid & 63;
  int l31 = l & 31, hi = l >> 5;
  if (tid < 96) {
    int idx = tile * 96 + tid;
    bool v = idx < cnt;
    toks[tid] = list[eoff[e] + (v ? idx : 0)];
    wts[tid] = v ? wlist[eoff[e] + idx] : 0.f;
  }
  __syncthreads();
#pragma unroll
  for (int s = 0; s < 12; ++s) {
    int sl = s * 512 + tid;
    int ent = sl >> 6, ll = sl & 63;
    int ks = ent / 3, t3 = ent - ks * 3;
    int tok = toks[t3 * 32 + (ll & 31)];
    const float* src = xmoe + (size_t)tok * 512 + ks * 16 + (ll >> 5) * 8;
    float4 v0 = *(const float4*)src;
    float4 v1 = *(const float4*)(src + 4);
    u32x4 u;
    u.x = (unsigned)f2bf(v0.x) | ((unsigned)f2bf(v0.y) << 16);
    u.y = (unsigned)f2bf(v0.z) | ((unsigned)f2bf(v0.w) << 16);
    u.z = (unsigned)f2bf(v1.x) | ((unsigned)f2bf(v1.y) << 16);
    u.w = (unsigned)f2bf(v1.z) | ((unsigned)f2bf(v1.w) << 16);
    *(u32x4*)(smem + ent * 1024 + ll * 16) = u;
  }
  f32x16 acc00, acc01, acc02, acc10, acc11, acc12;
#pragma unroll
  for (int i = 0; i < 16; ++i) {
    acc00[i] = 0.f; acc01[i] = 0.f; acc02[i] = 0.f;
    acc10[i] = 0.f; acc11[i] = 0.f; acc12[i] = 0.f;
  }
  __syncthreads();

  const size_t dstE1 = (size_t)64 * 32 * 512;
  const size_t dstE2 = (size_t)16 * 128 * 512;
  int rot1 = w * 4;      // GEMM1 ks rotation (waves 4 apart -> SIMD pair 16 apart)
  int rot2 = w * 2;      // GEMM2 fs rotation (SIMD pair 8 apart)
  for (int it = 0; it < 8; ++it) {
    f32x16 z0, z1, z2;
#pragma unroll
    for (int i = 0; i < 16; ++i) { z0[i] = 0.f; z1[i] = 0.f; z2[i] = 0.f; }
    const unsigned short* w1p =
        W1Pk + (size_t)e * dstE1 + ((size_t)(it * 8 + w) * 32) * 512 + l * 8;
#pragma unroll 8
    for (int ks0 = 0; ks0 < 32; ++ks0) {
      int ks = (ks0 + rot1) & 31;
      bf16x8 a = *(const bf16x8*)(w1p + (size_t)ks * 512);
      bf16x8 b0 = ld_frag(smem + (ks * 3 + 0) * 1024 + l * 16);
      bf16x8 b1 = ld_frag(smem + (ks * 3 + 1) * 1024 + l * 16);
      bf16x8 b2 = ld_frag(smem + (ks * 3 + 2) * 1024 + l * 16);
      z0 = __builtin_amdgcn_mfma_f32_32x32x16_bf16(a, b0, z0, 0, 0, 0);
      z1 = __builtin_amdgcn_mfma_f32_32x32x16_bf16(a, b1, z1, 0, 0, 0);
      z2 = __builtin_amdgcn_mfma_f32_32x32x16_bf16(a, b2, z2, 0, 0, 0);
    }
#define GELU_STORE(Z, T3)                                                       \
  {                                                                             \
    _Pragma("unroll") for (int rq = 0; rq < 4; ++rq) {                          \
      int fb = w * 32 + 8 * rq + 4 * hi;                                        \
      float4 bv = *(const float4*)(b1g + e * 2048 + it * 256 + fb);             \
      float g0 = gelu_tanh(Z[4 * rq + 0] + bv.x);                               \
      float g1 = gelu_tanh(Z[4 * rq + 1] + bv.y);                               \
      float g2 = gelu_tanh(Z[4 * rq + 2] + bv.z);                               \
      float g3 = gelu_tanh(Z[4 * rq + 3] + bv.w);                               \
      u32x2 p;                                                                  \
      p.x = (unsigned)f2bf(g0) | ((unsigned)f2bf(g1) << 16);                    \
      p.y = (unsigned)f2bf(g2) | ((unsigned)f2bf(g3) << 16);                    \
      int ent = (w * 2 + (rq >> 1)) * 3 + (T3);                                 \
      int lanep = l31 + 32 * (rq & 1);                                          \
      *(u32x2*)(smem + HS_OFF + ent * 1024 + lanep * 16 + hi * 8) = p;          \
    }                                                                           \
  }
    GELU_STORE(z0, 0)
    GELU_STORE(z1, 1)
    GELU_STORE(z2, 2)
    __syncthreads();
    const unsigned short* w2a =
        W2Pk + (size_t)e * dstE2 + ((size_t)(w * 2) * 128 + it * 16) * 512 + l * 8;
    const unsigned short* w2b = w2a + (size_t)128 * 512;
#pragma unroll 8
    for (int fs0 = 0; fs0 < 16; ++fs0) {
      int fs = (fs0 + rot2) & 15;
      bf16x8 a0 = *(const bf16x8*)(w2a + (size_t)fs * 512);
      bf16x8 a1 = *(const bf16x8*)(w2b + (size_t)fs * 512);
      bf16x8 h0 = ld_frag(smem + HS_OFF + (fs * 3 + 0) * 1024 + l * 16);
      bf16x8 h1 = ld_frag(smem + HS_OFF + (fs * 3 + 1) * 1024 + l * 16);
      bf16x8 h2 = ld_frag(smem + HS_OFF + (fs * 3 + 2) * 1024 + l * 16);
      acc00 = __builtin_amdgcn_mfma_f32_32x32x16_bf16(a0, h0, acc00, 0, 0, 0);
      acc01 = __builtin_amdgcn_mfma_f32_32x32x16_bf16(a0, h1, acc01, 0, 0, 0);
      acc02 = __builtin_amdgcn_mfma_f32_32x32x16_bf16(a0, h2, acc02, 0, 0, 0);
      acc10 = __builtin_amdgcn_mfma_f32_32x32x16_bf16(a1, h0, acc10, 0, 0, 0);
      acc11 = __builtin_amdgcn_mfma_f32_32x32x16_bf16(a1, h1, acc11, 0, 0, 0);
      acc12 = __builtin_amdgcn_mfma_f32_32x32x16_bf16(a1, h2, acc12, 0, 0, 0);
    }
    __syncthreads();
  }
#define EPI_STORE(ACC, JC, T3)                                                  \
  {                                                                             \
    _Pragma("unroll") for (int rq = 0; rq < 4; ++rq) {                          \
      int c0 = (w * 2 + (JC)) * 32 + 8 * rq + 4 * hi;                           \
      float4 b2v = *(const float4*)(b2g + e * 512 + c0);                        \
      int tok = (T3)*32 + l31;                                                  \
      float wt = wts[tok];                                                      \
      u32x2 p;                                                                  \
      p.x = (unsigned)f2bf((ACC[4 * rq + 0] + b2v.x) * wt) |                    \
            ((unsigned)f2bf((ACC[4 * rq + 1] + b2v.y) * wt) << 16);             \
      p.y = (unsigned)f2bf((ACC[4 * rq + 2] + b2v.z) * wt) |                    \
            ((unsigned)f2bf((ACC[4 * rq + 3] + b2v.w) * wt) << 16);             \
      *(u32x2*)(smem + tok * 1024 + ((c0 * 2) ^ ((tok & 7) << 4))) = p;         \
    }                                                                           \
  }
  EPI_STORE(acc00, 0, 0)
  EPI_STORE(acc01, 0, 1)
  EPI_STORE(acc02, 0, 2)
  EPI_STORE(acc10, 1, 0)
  EPI_STORE(acc11, 1, 1)
  EPI_STORE(acc12, 1, 2)
  __syncthreads();
#pragma unroll
  for (int s = 0; s < 12; ++s) {
    int i = tid + s * 512;
    int row = i >> 6, g = i & 63;
    if (row < valid) {
      u32x4 v = *(u32x4*)(smem + row * 1024 + ((g * 16) ^ ((row & 7) << 4)));
      *(u32x4*)(Yb + (size_t)(base + row) * 512 + g * 8) = v;
    }
  }
}

// K8: head bf16 MFMA GEMM
__global__ __launch_bounds__(256) void k_head(const unsigned short* __restrict__ Yb,
                                              const int* __restrict__ tokpos,
                                              const unsigned short* __restrict__ headPk,
                                              const float* __restrict__ headB,
                                              float* __restrict__ out) {
  __shared__ __align__(16) char As[16384];
  __shared__ int tp[256];
  int tid = threadIdx.x;
  int w = tid >> 6, l = tid & 63;
  int l31 = l & 31, hi = l >> 5;
  int mg = w & 1, ng = w >> 1;
  int bm = blockIdx.x * 128, by = blockIdx.y;
  tp[tid] = tokpos[bm * 2 + tid];
  f32x16 acc00, acc01, acc10, acc11;
#pragma unroll
  for (int i = 0; i < 16; ++i) { acc00[i] = 0.f; acc01[i] = 0.f; acc10[i] = 0.f; acc11[i] = 0.f; }
  int nblk0 = by * 4 + ng * 2;
  __syncthreads();
  for (int kb = 0; kb < 8; ++kb) {
#pragma unroll
    for (int s = 0; s < 4; ++s) {
      int i = tid + s * 256;
      int row = i >> 3, g = i & 7;
      int p1 = tp[row * 2], p2 = tp[row * 2 + 1];
      u32x4 va = *(const u32x4*)(Yb + (size_t)p1 * 512 + kb * 64 + g * 8);
      u32x4 vb = *(const u32x4*)(Yb + (size_t)p2 * 512 + kb * 64 + g * 8);
      u32x4 o;
      o.x = (unsigned)f2bf(bflo(va.x) + bflo(vb.x)) | ((unsigned)f2bf(bfhi(va.x) + bfhi(vb.x)) << 16);
      o.y = (unsigned)f2bf(bflo(va.y) + bflo(vb.y)) | ((unsigned)f2bf(bfhi(va.y) + bfhi(vb.y)) << 16);
      o.z = (unsigned)f2bf(bflo(va.z) + bflo(vb.z)) | ((unsigned)f2bf(bfhi(va.z) + bfhi(vb.z)) << 16);
      o.w = (unsigned)f2bf(bflo(va.w) + bflo(vb.w)) | ((unsigned)f2bf(bfhi(va.w) + bfhi(vb.w)) << 16);
      *(u32x4*)(As + row * 128 + ((g * 16) ^ ((row & 7) << 4))) = o;
    }
    __syncthreads();
#pragma unroll
    for (int ks = 0; ks < 4; ++ks) {
      int r0 = mg * 64 + l31, r1 = r0 + 32;
      int kbyte = ks * 32 + hi * 16;
      bf16x8 a0 = ld_frag(As + r0 * 128 + (kbyte ^ ((r0 & 7) << 4)));
      bf16x8 a1 = ld_frag(As + r1 * 128 + (kbyte ^ ((r1 & 7) << 4)));
      const unsigned short* hp = headPk + ((size_t)nblk0 * 32 + kb * 4 + ks) * 512 + l * 8;
      bf16x8 b0 = *(const bf16x8*)hp;
      bf16x8 b1 = *(const bf16x8*)(hp + 32 * 512);
      acc00 = __builtin_amdgcn_mfma_f32_32x32x16_bf16(a0, b0, acc00, 0, 0, 0);
      acc01 = __builtin_amdgcn_mfma_f32_32x32x16_bf16(a0, b1, acc01, 0, 0, 0);
      acc10 = __builtin_amdgcn_mfma_f32_32x32x16_bf16(a1, b0, acc10, 0, 0, 0);
      acc11 = __builtin_amdgcn_mfma_f32_32x32x16_bf16(a1, b1, acc11, 0, 0, 0);
    }
    __syncthreads();
  }
#pragma unroll
  for (int mf = 0; mf < 2; ++mf) {
#pragma unroll
    for (int nf = 0; nf < 2; ++nf) {
      int nc = by * 128 + ng * 64 + nf * 32 + l31;
      float hb = headB[nc];
#pragma unroll
      for (int r = 0; r < 16; ++r) {
        int m = bm + mg * 64 + mf * 32 + (r & 3) + 8 * (r >> 2) + 4 * hi;
        float v;
        if (mf == 0) v = (nf == 0) ? acc00[r] : acc01[r];
        else         v = (nf == 0) ? acc10[r] : acc11[r];
        out[(size_t)m * 256 + nc] = v + hb;
      }
    }
  }
}

extern "C" void kernel_launch(void* const* d_in, const int* in_sizes, int n_in,
                              void* d_out, int out_size, void* d_ws, size_t ws_size,
                              hipStream_t stream) {
  (void)in_sizes; (void)n_in; (void)out_size; (void)ws_size;
  const int* seq     = (const int*)d_in[0];
  const float* emb   = (const float*)d_in[1];
  const float* phi_w = (const float*)d_in[2];
  const float* phi_b = (const float*)d_in[3];
  const float* amp_w = (const float*)d_in[4];
  const float* amp_b = (const float*)d_in[5];
  const float* gate_w = (const float*)d_in[6];
  const float* gate_b = (const float*)d_in[7];
  const float* w1 = (const float*)d_in[8];
  const float* b1 = (const float*)d_in[9];
  const float* w2 = (const float*)d_in[10];
  const float* b2 = (const float*)d_in[11];
  const float* head_w = (const float*)d_in[12];
  const float* head_b = (const float*)d_in[13];
  float* out = (float*)d_out;

  char* ws = (char*)d_ws;
  const size_t BUF = 16777216;
  float* X    = (float*)(ws);                         // Xhi|Xlo -> xmoe (in place)
  float* COSb = (float*)(ws + BUF);                   // cos -> Yb (bf16)
  float* SINb = (float*)(ws + 2 * BUF);               // sin -> W1Pk (bf16)
  float* SIGb = (float*)(ws + 3 * BUF);               // sig -> W2Pk (bf16)
  unsigned short* XhiP = (unsigned short*)X;          // 8MB
  unsigned short* XloP = XhiP + (size_t)8192 * 512;   // 8MB
  unsigned short* Yb   = (unsigned short*)COSb;
  unsigned short* W1Pk = (unsigned short*)SINb;
  unsigned short* W2Pk = (unsigned short*)SIGb;
  char* sm = ws + 4 * BUF;
  int*      e01p   = (int*)(sm);                      // 32KB
  unsigned* w01p   = (unsigned*)(sm + 32768);         // 32KB
  int*      list   = (int*)(sm + 65536);              // 64KB
  float*    wlist  = (float*)(sm + 131072);           // 64KB
  int*      tokpos = (int*)(sm + 196608);             // 64KB
  int*      counts = (int*)(sm + 262144);
  int*      eoff   = (int*)(sm + 262144 + 64);
  unsigned short* headPk = (unsigned short*)(sm + 266240);  // 256KB
  int*      tmap   = (int*)(sm + 266240 + 262144);          // 272 ints

  k_embed2<<<2048, 256, 0, stream>>>(seq, emb, XhiP, XloP);
  k_pack_b<<<dim3(8, 1, 1), 256, 0, stream>>>(head_w, 256, 0, headPk, 0, 32);
  k_phi<<<dim3(64, 8), 256, 0, stream>>>(XhiP, XloP, phi_w, phi_b, amp_w, amp_b,
                                         COSb, SINb, SIGb);
  k_scan<<<32, 256, 0, stream>>>(COSb, SINb, SIGb, X, out + 2097152);
  k_pack_b<<<dim3(64, 1, 8), 256, 0, stream>>>(w1, 2048, (size_t)512 * 2048, W1Pk,
                                               (size_t)64 * 32 * 512, 32);
  k_pack_b<<<dim3(16, 4, 8), 256, 0, stream>>>(w2, 512, (size_t)2048 * 512, W2Pk,
                                               (size_t)16 * 128 * 512, 128);
  k_gate<<<256, 256, 0, stream>>>(X, gate_w, gate_b, e01p, w01p);
  k_build<<<1, 256, 0, stream>>>(e01p, w01p, list, wlist, counts, eoff, tokpos, tmap);
  k_ffn<<<192, 512, 0, stream>>>(X, list, wlist, counts, eoff, tmap,
                                 W1Pk, b1, W2Pk, b2, Yb);
  k_head<<<dim3(64, 2), 256, 0, stream>>>(Yb, tokpos, headPk, head_b, out);
}

// Round 16
// 393.193 us; speedup vs baseline: 1.1019x; 1.1019x over previous
//
#include <hip/hip_runtime.h>
#include <hip/hip_fp16.h>
#include <math.h>

// ---------------------------------------------------------------------------
// SovereignLeviathanV2  round 16 = round 12 verbatim (best verified: 393.8us).
// r13 (16-wave fg-split), r14 (unroll 16), r15 (wave rotation) all regressed
// or were neutral -> k_ffn v4 @147us is the structural floor of this design.
//  - k_embed2: frag-packed Xhi/Xlo bf16 split-precision
//  - k_phi: bf16x3 split-precision MFMA (fp32-grade, tesla-gate safe)
//  - k_scan: producer-consumer (1 compute wave + 3 loader waves, LDS ring)
//  - k_ffn: 96-token tiles, 512 thr / 8 waves, frag-packed LDS, tmap-balanced
//  - k_head: bf16 MFMA with Yb[p1]+Yb[p2] gather-sum
// ---------------------------------------------------------------------------

#define PI_F 3.14159265358979323846f
#define HARM_F 1.04719755119659774615f
#define INV_HARM_F 0.95492965855137201461f
#define TOL_F 0.15f

typedef float f32x16 __attribute__((ext_vector_type(16)));
typedef __bf16 bf16x8 __attribute__((ext_vector_type(8)));
typedef unsigned int u32x4 __attribute__((ext_vector_type(4)));
typedef unsigned int u32x2 __attribute__((ext_vector_type(2)));

__device__ __forceinline__ float bflo(unsigned u) { return __uint_as_float(u << 16); }
__device__ __forceinline__ float bfhi(unsigned u) { return __uint_as_float(u & 0xFFFF0000u); }
__device__ __forceinline__ unsigned short f2bf(float x) {
  unsigned u = __float_as_uint(x);
  unsigned r = (u + 0x7FFFu + ((u >> 16) & 1u)) >> 16;
  return (unsigned short)r;
}
__device__ __forceinline__ bf16x8 ld_frag(const void* p) {
  u32x4 v = *(const u32x4*)p;
  return __builtin_bit_cast(bf16x8, v);
}
__device__ __forceinline__ float tanh_fast(float z) {
  float zc = fminf(10.f, fmaxf(-10.f, z));
  float e2 = __expf(zc + zc);
  return (e2 - 1.f) / (e2 + 1.f);
}
__device__ __forceinline__ float sigmoid_fast(float z) {
  return 1.f / (1.f + __expf(-z));
}
__device__ __forceinline__ float gelu_tanh(float x) {
  float x3 = x * x * x;
  float t = 0.79788456080286535588f * (x + 0.044715f * x3);
  return 0.5f * x * (1.f + tanh_fast(t));
}
__device__ __forceinline__ void sincos_poly(float a, float* sn, float* cs) {
  float q = rintf(a * 0.63661977236758134f);
  int iq = (int)q;
  float t = fmaf(-q, 1.57079637050628662f, a);
  t = fmaf(q, 4.37113883e-8f, t);
  float t2 = t * t;
  float sp = t * fmaf(t2, fmaf(t2, fmaf(t2, -1.9515296e-4f, 8.3321609e-3f),
                               -1.6666654e-1f), 1.f);
  float cp = fmaf(t2 * t2,
                  fmaf(t2, fmaf(t2, 2.4433158e-5f, -1.3887316e-3f), 4.1666646e-2f),
                  fmaf(t2, -0.5f, 1.f));
  int m = iq & 3;
  bool swap = (m & 1) != 0;
  float ss = swap ? cp : sp;
  float cc = swap ? sp : cp;
  *sn = (m & 2) ? -ss : ss;
  *cs = ((m + 1) & 2) ? -cc : cc;
}

// K1 v2: frag-packed Xhi/Xlo. Entry ent = tb*32+ks: lane l holds
// X[tok=tb*32+(l&31)][k=ks*16+(l>>5)*8+j] as bf16 hi + bf16 residual lo.
__global__ void k_embed2(const int* __restrict__ seq, const float* __restrict__ emb,
                         unsigned short* __restrict__ XhiP,
                         unsigned short* __restrict__ XloP) {
  int gid = blockIdx.x * 256 + threadIdx.x;  // 0..524287
  int ent = gid >> 6, l = gid & 63;
  int tb = ent >> 5, ks = ent & 31;
  int tok = tb * 32 + (l & 31);
  int k0 = ks * 16 + (l >> 5) * 8;
  const float* src = emb + (size_t)seq[tok] * 512 + k0;
  float4 v0 = *(const float4*)src;
  float4 v1 = *(const float4*)(src + 4);
  float vv[8] = {v0.x, v0.y, v0.z, v0.w, v1.x, v1.y, v1.z, v1.w};
  unsigned h[8], lo[8];
#pragma unroll
  for (int j = 0; j < 8; ++j) {
    h[j] = f2bf(vv[j]);
    lo[j] = f2bf(vv[j] - bflo(h[j]));
  }
  u32x4 H, L;
  H.x = h[0] | (h[1] << 16);  H.y = h[2] | (h[3] << 16);
  H.z = h[4] | (h[5] << 16);  H.w = h[6] | (h[7] << 16);
  L.x = lo[0] | (lo[1] << 16); L.y = lo[2] | (lo[3] << 16);
  L.z = lo[4] | (lo[5] << 16); L.w = lo[6] | (lo[7] << 16);
  *(u32x4*)(XhiP + (size_t)ent * 512 + l * 8) = H;
  *(u32x4*)(XloP + (size_t)ent * 512 + l * 8) = L;
}

// ---------------------------------------------------------------------------
// Generic B-operand frag pack: src fp32 [K][N] (row-major, leading dim ld)
// -> bf16 frag entries. Entry (nb, ksGlobal): 64 lanes x 16B, lane l holds
// src[ksGlobal*16 + (l>>5)*8 + j][nb*32 + (l&31)], j=0..7.
// ---------------------------------------------------------------------------
__global__ __launch_bounds__(256) void k_pack_b(const float* __restrict__ src, int ld,
                                                size_t srcE, unsigned short* __restrict__ dst,
                                                size_t dstE, int fragKtot) {
  __shared__ float Ls[512 * 33];
  int nb = blockIdx.x, kseg = blockIdx.y, e = blockIdx.z;
  const float* s = src + (size_t)e * srcE + (size_t)kseg * 512 * ld + nb * 32;
  unsigned short* d = dst + (size_t)e * dstE + ((size_t)(nb * fragKtot + kseg * 32)) * 512;
  int tid = threadIdx.x;
#pragma unroll
  for (int q = 0; q < 16; ++q) {
    int i = tid + q * 256;
    int row = i >> 3, c4 = i & 7;
    float4 v = *(const float4*)(s + (size_t)row * ld + c4 * 4);
    Ls[row * 33 + c4 * 4 + 0] = v.x;
    Ls[row * 33 + c4 * 4 + 1] = v.y;
    Ls[row * 33 + c4 * 4 + 2] = v.z;
    Ls[row * 33 + c4 * 4 + 3] = v.w;
  }
  __syncthreads();
#pragma unroll
  for (int q = 0; q < 8; ++q) {
    int i = tid + q * 256;
    int ks = i >> 6, l = i & 63;
    int col = l & 31, kb = (l >> 5) * 8 + ks * 16;
    u32x4 o;
    o.x = (unsigned)f2bf(Ls[(kb + 0) * 33 + col]) | ((unsigned)f2bf(Ls[(kb + 1) * 33 + col]) << 16);
    o.y = (unsigned)f2bf(Ls[(kb + 2) * 33 + col]) | ((unsigned)f2bf(Ls[(kb + 3) * 33 + col]) << 16);
    o.z = (unsigned)f2bf(Ls[(kb + 4) * 33 + col]) | ((unsigned)f2bf(Ls[(kb + 5) * 33 + col]) << 16);
    o.w = (unsigned)f2bf(Ls[(kb + 6) * 33 + col]) | ((unsigned)f2bf(Ls[(kb + 7) * 33 + col]) << 16);
    *(u32x4*)(d + (size_t)ks * 512 + l * 8) = o;
  }
}

// ---------------------------------------------------------------------------
// K2 v5: bf16x3 MFMA phi+amp GEMM. Block = (128 tokens, 128 cols), 256 thr /
// 4 waves. Wave w = token-frag tb = blk*4+w; per ks: stage W hi/lo (dbuf LDS,
// wave w stages nb=w), 12 MFMA (4 nb x {HH, LH, HL}).
// ---------------------------------------------------------------------------
__global__ __launch_bounds__(256, 3) void k_phi(
    const unsigned short* __restrict__ XhiP, const unsigned short* __restrict__ XloP,
    const float* __restrict__ phiW, const float* __restrict__ phiB,
    const float* __restrict__ ampW, const float* __restrict__ ampB,
    float* __restrict__ cosO, float* __restrict__ sinO, float* __restrict__ sigO) {
  __shared__ __align__(16) char wlds[2][8][1024];  // [buf][nb*2+hi/lo][64 lanes x 16B]
  int tid = threadIdx.x;
  int w = tid >> 6, l = tid & 63;
  int l31 = l & 31, hi = l >> 5;
  int by = blockIdx.y;
  const float* Bsrc = (by < 4) ? phiW : ampW;
  const float* bias = (by < 4) ? phiB : ampB;
  int cb = (by & 3) * 128;

#define STAGE_W(KS, BUF)                                                        \
  {                                                                             \
    const float* wsrc = Bsrc + (size_t)((KS)*16 + hi * 8) * 512 + cb + w * 32 + l31; \
    float v0 = wsrc[0],    v1 = wsrc[512],  v2 = wsrc[1024], v3 = wsrc[1536];   \
    float v4 = wsrc[2048], v5 = wsrc[2560], v6 = wsrc[3072], v7 = wsrc[3584];   \
    unsigned h0 = f2bf(v0), h1 = f2bf(v1), h2 = f2bf(v2), h3 = f2bf(v3);        \
    unsigned h4 = f2bf(v4), h5 = f2bf(v5), h6 = f2bf(v6), h7 = f2bf(v7);        \
    u32x4 H, L;                                                                 \
    H.x = h0 | (h1 << 16); H.y = h2 | (h3 << 16);                               \
    H.z = h4 | (h5 << 16); H.w = h6 | (h7 << 16);                               \
    L.x = (unsigned)f2bf(v0 - bflo(h0)) | ((unsigned)f2bf(v1 - bflo(h1)) << 16); \
    L.y = (unsigned)f2bf(v2 - bflo(h2)) | ((unsigned)f2bf(v3 - bflo(h3)) << 16); \
    L.z = (unsigned)f2bf(v4 - bflo(h4)) | ((unsigned)f2bf(v5 - bflo(h5)) << 16); \
    L.w = (unsigned)f2bf(v6 - bflo(h6)) | ((unsigned)f2bf(v7 - bflo(h7)) << 16); \
    *(u32x4*)(&wlds[BUF][w * 2 + 0][l * 16]) = H;                               \
    *(u32x4*)(&wlds[BUF][w * 2 + 1][l * 16]) = L;                               \
  }

  int tb = blockIdx.x * 4 + w;
  const unsigned short* xh_base = XhiP + ((size_t)tb * 32) * 512 + l * 8;
  const unsigned short* xl_base = XloP + ((size_t)tb * 32) * 512 + l * 8;
  f32x16 a0, a1, a2, a3;
#pragma unroll
  for (int i = 0; i < 16; ++i) { a0[i] = 0.f; a1[i] = 0.f; a2[i] = 0.f; a3[i] = 0.f; }

  STAGE_W(0, 0);
  for (int ks = 0; ks < 32; ++ks) {
    __syncthreads();
    if (ks + 1 < 32) {
      if (((ks + 1) & 1) == 0) STAGE_W(ks + 1, 0) else STAGE_W(ks + 1, 1)
    }
    bf16x8 xh = *(const bf16x8*)(xh_base + (size_t)ks * 512);
    bf16x8 xl = *(const bf16x8*)(xl_base + (size_t)ks * 512);
    const char (*wb)[1024] = wlds[ks & 1];
    bf16x8 wh0 = ld_frag(&wb[0][l * 16]), wl0 = ld_frag(&wb[1][l * 16]);
    bf16x8 wh1 = ld_frag(&wb[2][l * 16]), wl1 = ld_frag(&wb[3][l * 16]);
    bf16x8 wh2 = ld_frag(&wb[4][l * 16]), wl2 = ld_frag(&wb[5][l * 16]);
    bf16x8 wh3 = ld_frag(&wb[6][l * 16]), wl3 = ld_frag(&wb[7][l * 16]);
    a0 = __builtin_amdgcn_mfma_f32_32x32x16_bf16(xh, wh0, a0, 0, 0, 0);
    a1 = __builtin_amdgcn_mfma_f32_32x32x16_bf16(xh, wh1, a1, 0, 0, 0);
    a2 = __builtin_amdgcn_mfma_f32_32x32x16_bf16(xh, wh2, a2, 0, 0, 0);
    a3 = __builtin_amdgcn_mfma_f32_32x32x16_bf16(xh, wh3, a3, 0, 0, 0);
    a0 = __builtin_amdgcn_mfma_f32_32x32x16_bf16(xl, wh0, a0, 0, 0, 0);
    a1 = __builtin_amdgcn_mfma_f32_32x32x16_bf16(xl, wh1, a1, 0, 0, 0);
    a2 = __builtin_amdgcn_mfma_f32_32x32x16_bf16(xl, wh2, a2, 0, 0, 0);
    a3 = __builtin_amdgcn_mfma_f32_32x32x16_bf16(xl, wh3, a3, 0, 0, 0);
    a0 = __builtin_amdgcn_mfma_f32_32x32x16_bf16(xh, wl0, a0, 0, 0, 0);
    a1 = __builtin_amdgcn_mfma_f32_32x32x16_bf16(xh, wl1, a1, 0, 0, 0);
    a2 = __builtin_amdgcn_mfma_f32_32x32x16_bf16(xh, wl2, a2, 0, 0, 0);
    a3 = __builtin_amdgcn_mfma_f32_32x32x16_bf16(xh, wl3, a3, 0, 0, 0);
  }

  int tokBase = blockIdx.x * 128 + w * 32;
#define PHI_EPI(ACC, NB)                                                        \
  {                                                                             \
    int c = cb + (NB)*32 + l31;                                                 \
    float bs = bias[c];                                                         \
    if (by < 4) {                                                               \
      _Pragma("unroll") for (int r = 0; r < 16; ++r) {                          \
        int tok = tokBase + (r & 3) + 8 * (r >> 2) + 4 * hi;                    \
        float z = ACC[r] + bs;                                                  \
        float a = tanh_fast(z) * PI_F;                                          \
        float nr = rintf(a * INV_HARM_F) * HARM_F;                              \
        if (fabsf(a - nr) < TOL_F) a = nr;                                      \
        float sn, cs;                                                           \
        sincos_poly(a, &sn, &cs);                                               \
        cosO[(size_t)tok * 512 + c] = cs;                                       \
        sinO[(size_t)tok * 512 + c] = sn;                                       \
      }                                                                         \
    } else {                                                                    \
      _Pragma("unroll") for (int r = 0; r < 16; ++r) {                          \
        int tok = tokBase + (r & 3) + 8 * (r >> 2) + 4 * hi;                    \
        sigO[(size_t)tok * 512 + c] = sigmoid_fast(ACC[r] + bs);                \
      }                                                                         \
    }                                                                           \
  }
  PHI_EPI(a0, 0)
  PHI_EPI(a1, 1)
  PHI_EPI(a2, 2)
  PHI_EPI(a3, 3)
}

// ---------------------------------------------------------------------------
// K3 v3: producer-consumer toroidal scan. 32 blocks x 256 thr (4 waves).
// wave0 computes 64 chains; waves 1-3 stage cos/sin/sig 64-step chunks into
// double-buffered LDS (2x3x16KB = 96KB).
// ---------------------------------------------------------------------------
__global__ __launch_bounds__(256, 1) void k_scan(const float* __restrict__ cosb,
                                                 const float* __restrict__ sinb,
                                                 const float* __restrict__ sigb,
                                                 float* __restrict__ xmoe,
                                                 float* __restrict__ nstate) {
  __shared__ float lds[2][3][64 * 64];
  int tid = threadIdx.x;
  int wv = tid >> 6, l = tid & 63;
  int b = blockIdx.x >> 3;
  int c0 = (blockIdx.x & 7) << 6;
  size_t base = ((size_t)b * 2048) * 512 + c0;

#define SCAN_STAGE(SRC, K, BUF)                                                \
  {                                                                            \
    float4 tmp[16];                                                            \
    size_t sb = base + ((size_t)(K) * 64 + tq) * 512 + cq * 4;                 \
    _Pragma("unroll") for (int t4 = 0; t4 < 16; ++t4)                          \
      tmp[t4] = *(const float4*)((SRC) + sb + (size_t)t4 * 4 * 512);           \
    _Pragma("unroll") for (int t4 = 0; t4 < 16; ++t4)                          \
      *(float4*)(&lds[BUF][wv - 1][(t4 * 4 + tq) * 64 + cq * 4]) = tmp[t4];    \
  }

  if (wv > 0) {
    const float* src = (wv == 1) ? cosb : (wv == 2) ? sinb : sigb;
    int tq = l >> 4, cq = l & 15;
    SCAN_STAGE(src, 0, 0);
    __syncthreads();
    for (int k = 0; k < 32; ++k) {
      if (k + 1 < 32) {
        if (((k + 1) & 1) == 0) SCAN_STAGE(src, k + 1, 0)
        else                    SCAN_STAGE(src, k + 1, 1)
      }
      __syncthreads();
    }
  } else {
    __syncthreads();
    float state = 0.f;
    for (int k = 0; k < 32; ++k) {
      const float* bufC = &lds[k & 1][0][0];
      const float* bufS = &lds[k & 1][1][0];
      const float* bufG = &lds[k & 1][2][0];
      size_t outb = base + (size_t)k * 64 * 512 + l;
#pragma unroll
      for (int tt = 0; tt < 64; ++tt) {
        float pc = bufC[tt * 64 + l];
        float ps = bufS[tt * 64 + l];
        float pg = bufG[tt * 64 + l];
        float st = fmaf(pc + ps, state, -ps);
        st = fminf(1.f, fmaxf(-1.f, st));
        state = st;
        xmoe[outb + (size_t)tt * 512] = pg * st;
      }
      __syncthreads();
    }
    nstate[(size_t)b * 512 + c0 + l] = state;
  }
}

// K4: gate logits + softmax + top2 -> packed e01p/w01p
__global__ __launch_bounds__(256) void k_gate(const float* __restrict__ xmoe,
                                              const float* __restrict__ gw_g,
                                              const float* __restrict__ gb,
                                              int* __restrict__ e01p,
                                              unsigned* __restrict__ w01p) {
  __shared__ float gw[4096];
  int tid = threadIdx.x;
  for (int i = tid; i < 4096; i += 256) gw[i] = gw_g[i];
  __syncthreads();
  int tok = blockIdx.x * 32 + (tid >> 3);
  int e = tid & 7;
  float acc = gb[e];
  const float4* xr = (const float4*)(xmoe + (size_t)tok * 512);
  for (int k4 = 0; k4 < 128; ++k4) {
    float4 x = xr[k4];
    acc += x.x * gw[(k4 * 4 + 0) * 8 + e];
    acc += x.y * gw[(k4 * 4 + 1) * 8 + e];
    acc += x.z * gw[(k4 * 4 + 2) * 8 + e];
    acc += x.w * gw[(k4 * 4 + 3) * 8 + e];
  }
  float m = acc;
  m = fmaxf(m, __shfl_xor(m, 1));
  m = fmaxf(m, __shfl_xor(m, 2));
  m = fmaxf(m, __shfl_xor(m, 4));
  float p = expf(acc - m);
  float ss = p;
  ss += __shfl_xor(ss, 1); ss += __shfl_xor(ss, 2); ss += __shfl_xor(ss, 4);
  p /= ss;
  float v1 = p; int i1 = e;
  {
    float ov; int oi;
    ov = __shfl_xor(v1, 1); oi = __shfl_xor(i1, 1);
    if (ov > v1 || (ov == v1 && oi < i1)) { v1 = ov; i1 = oi; }
    ov = __shfl_xor(v1, 2); oi = __shfl_xor(i1, 2);
    if (ov > v1 || (ov == v1 && oi < i1)) { v1 = ov; i1 = oi; }
    ov = __shfl_xor(v1, 4); oi = __shfl_xor(i1, 4);
    if (ov > v1 || (ov == v1 && oi < i1)) { v1 = ov; i1 = oi; }
  }
  float v2 = (e == i1) ? -1.f : p; int i2 = e;
  {
    float ov; int oi;
    ov = __shfl_xor(v2, 1); oi = __shfl_xor(i2, 1);
    if (ov > v2 || (ov == v2 && oi < i2)) { v2 = ov; i2 = oi; }
    ov = __shfl_xor(v2, 2); oi = __shfl_xor(i2, 2);
    if (ov > v2 || (ov == v2 && oi < i2)) { v2 = ov; i2 = oi; }
    ov = __shfl_xor(v2, 4); oi = __shfl_xor(i2, 4);
    if (ov > v2 || (ov == v2 && oi < i2)) { v2 = ov; i2 = oi; }
  }
  if (e == 0) {
    float s2 = v1 + v2;
    __half h1 = __float2half(v1 / s2), h2 = __float2half(v2 / s2);
    e01p[tok] = i1 | (i2 << 8);
    w01p[tok] = (unsigned)__half_as_ushort(h1) | ((unsigned)__half_as_ushort(h2) << 16);
  }
}

// K6: counts -> eoff -> scatter -> tmap (chunked XCD-balanced, 96-tok tiles)
__global__ void k_build(const int* __restrict__ e01p, const unsigned* __restrict__ w01p,
                        int* __restrict__ list, float* __restrict__ wlist,
                        int* __restrict__ counts, int* __restrict__ eoff,
                        int* __restrict__ tokpos, int* __restrict__ tmap) {
  __shared__ int cnt[8], cur[8];
  int tid = threadIdx.x, lane = tid & 63;
  if (tid < 8) cnt[tid] = 0;
  __syncthreads();
  for (int i = tid; i < 16384; i += 256) {
    int tok = i >> 1, j = i & 1;
    int ee = (e01p[tok] >> (8 * j)) & 255;
#pragma unroll
    for (int x = 0; x < 8; ++x) {
      unsigned long long m = __ballot(ee == x);
      if (m != 0ull && lane == (__ffsll((long long)m) - 1)) atomicAdd(&cnt[x], __popcll(m));
    }
  }
  __syncthreads();
  if (tid == 0) {
    int s = 0;
#pragma unroll
    for (int x = 0; x < 8; ++x) {
      cur[x] = s; eoff[x] = s; counts[x] = cnt[x]; s += cnt[x];
    }
  }
  __syncthreads();
  for (int i = tid; i < 272; i += 256) tmap[i] = -1;
  __syncthreads();
  if (tid == 0) {
    int ntiles = 0, tstart[8];
#pragma unroll
    for (int e = 0; e < 8; ++e) { tstart[e] = ntiles; ntiles += (cnt[e] + 95) / 96; }
    int q = ntiles >> 3, r = ntiles & 7;
    for (int e = 0; e < 8; ++e) {
      int nt = (cnt[e] + 95) / 96;
      for (int t = 0; t < nt; ++t) {
        int k = tstart[e] + t;
        int c, o;
        if (k < r * (q + 1)) { c = k / (q + 1); o = k - c * (q + 1); }
        else { int k2 = k - r * (q + 1); c = r + k2 / q; o = k2 - (k2 / q) * q; }
        tmap[8 * o + c] = (e << 16) | t;
      }
    }
  }
  __syncthreads();
  for (int i = tid; i < 16384; i += 256) {
    int tok = i >> 1, j = i & 1;
    int ee = (e01p[tok] >> (8 * j)) & 255;
    unsigned wp = w01p[tok];
    unsigned short us = (unsigned short)(j ? (wp >> 16) : (wp & 0xFFFFu));
    float w = __half2float(__ushort_as_half(us));
    int pos = 0;
#pragma unroll
    for (int x = 0; x < 8; ++x) {
      unsigned long long m = __ballot(ee == x);
      if (m == 0ull) continue;
      int leader = __ffsll((long long)m) - 1;
      int bb = 0;
      if (lane == leader) bb = atomicAdd(&cur[x], __popcll(m));
      bb = __shfl(bb, leader);
      if (ee == x) pos = bb + __popcll(m & ((1ull << lane) - 1ull));
    }
    list[pos] = tok;
    wlist[pos] = w;
    tokpos[i] = pos;
  }
}

// ---------------------------------------------------------------------------
// K7 v4: fused MoE FFN, 96-token tiles. Block = tmap tile, 512 thr / 8 waves.
// F-strips of 256 (8 its). GEMM1: wave w = 32f, z = 3 tok-frags. GEMM2:
// wave w = 64c, acc = 6 f32x16. Frag-packed LDS lane-linear (conflict-free).
// ---------------------------------------------------------------------------
#define HS_OFF 98304

__global__ __launch_bounds__(512, 2) void k_ffn(
    const float* __restrict__ xmoe, const int* __restrict__ list,
    const float* __restrict__ wlist, const int* __restrict__ counts,
    const int* __restrict__ eoff, const int* __restrict__ tmap,
    const unsigned short* __restrict__ W1Pk, const float* __restrict__ b1g,
    const unsigned short* __restrict__ W2Pk, const float* __restrict__ b2g,
    unsigned short* __restrict__ Yb) {
  int mp = tmap[blockIdx.x];
  if (mp < 0) return;
  int e = mp >> 16, tile = mp & 0xFFFF;
  int cnt = counts[e];
  int base = eoff[e] + tile * 96;
  int valid = cnt - tile * 96;
  if (valid > 96) valid = 96;
  __shared__ __align__(16) char smem[147456];  // Xs 96KB | Hs 48KB
  __shared__ int toks[96];
  __shared__ float wts[96];
  int tid = threadIdx.x;
  int w = tid >> 6, l = tid & 63;
  int l31 = l & 31, hi = l >> 5;
  if (tid < 96) {
    int idx = tile * 96 + tid;
    bool v = idx < cnt;
    toks[tid] = list[eoff[e] + (v ? idx : 0)];
    wts[tid] = v ? wlist[eoff[e] + idx] : 0.f;
  }
  __syncthreads();
  // stage Xs_packed: 96 entries (ks*3+t3) x 64 lanes x 16B
#pragma unroll
  for (int s = 0; s < 12; ++s) {
    int sl = s * 512 + tid;
    int ent = sl >> 6, ll = sl & 63;
    int ks = ent / 3, t3 = ent - ks * 3;
    int tok = toks[t3 * 32 + (ll & 31)];
    const float* src = xmoe + (size_t)tok * 512 + ks * 16 + (ll >> 5) * 8;
    float4 v0 = *(const float4*)src;
    float4 v1 = *(const float4*)(src + 4);
    u32x4 u;
    u.x = (unsigned)f2bf(v0.x) | ((unsigned)f2bf(v0.y) << 16);
    u.y = (unsigned)f2bf(v0.z) | ((unsigned)f2bf(v0.w) << 16);
    u.z = (unsigned)f2bf(v1.x) | ((unsigned)f2bf(v1.y) << 16);
    u.w = (unsigned)f2bf(v1.z) | ((unsigned)f2bf(v1.w) << 16);
    *(u32x4*)(smem + ent * 1024 + ll * 16) = u;
  }
  f32x16 acc00, acc01, acc02, acc10, acc11, acc12;
#pragma unroll
  for (int i = 0; i < 16; ++i) {
    acc00[i] = 0.f; acc01[i] = 0.f; acc02[i] = 0.f;
    acc10[i] = 0.f; acc11[i] = 0.f; acc12[i] = 0.f;
  }
  __syncthreads();

  const size_t dstE1 = (size_t)64 * 32 * 512;
  const size_t dstE2 = (size_t)16 * 128 * 512;
  for (int it = 0; it < 8; ++it) {
    // ---- GEMM1: ftile it*8 + w (32 f), 96 tokens ----
    f32x16 z0, z1, z2;
#pragma unroll
    for (int i = 0; i < 16; ++i) { z0[i] = 0.f; z1[i] = 0.f; z2[i] = 0.f; }
    const unsigned short* w1p =
        W1Pk + (size_t)e * dstE1 + ((size_t)(it * 8 + w) * 32) * 512 + l * 8;
#pragma unroll 8
    for (int ks = 0; ks < 32; ++ks) {
      bf16x8 a = *(const bf16x8*)(w1p + (size_t)ks * 512);
      bf16x8 b0 = ld_frag(smem + (ks * 3 + 0) * 1024 + l * 16);
      bf16x8 b1 = ld_frag(smem + (ks * 3 + 1) * 1024 + l * 16);
      bf16x8 b2 = ld_frag(smem + (ks * 3 + 2) * 1024 + l * 16);
      z0 = __builtin_amdgcn_mfma_f32_32x32x16_bf16(a, b0, z0, 0, 0, 0);
      z1 = __builtin_amdgcn_mfma_f32_32x32x16_bf16(a, b1, z1, 0, 0, 0);
      z2 = __builtin_amdgcn_mfma_f32_32x32x16_bf16(a, b2, z2, 0, 0, 0);
    }
    // bias + gelu -> Hs_packed (entry = fs*3 + t3, fs = w*2 + (rq>>1))
#define GELU_STORE(Z, T3)                                                       \
  {                                                                             \
    _Pragma("unroll") for (int rq = 0; rq < 4; ++rq) {                          \
      int fb = w * 32 + 8 * rq + 4 * hi;                                        \
      float4 bv = *(const float4*)(b1g + e * 2048 + it * 256 + fb);             \
      float g0 = gelu_tanh(Z[4 * rq + 0] + bv.x);                               \
      float g1 = gelu_tanh(Z[4 * rq + 1] + bv.y);                               \
      float g2 = gelu_tanh(Z[4 * rq + 2] + bv.z);                               \
      float g3 = gelu_tanh(Z[4 * rq + 3] + bv.w);                               \
      u32x2 p;                                                                  \
      p.x = (unsigned)f2bf(g0) | ((unsigned)f2bf(g1) << 16);                    \
      p.y = (unsigned)f2bf(g2) | ((unsigned)f2bf(g3) << 16);                    \
      int ent = (w * 2 + (rq >> 1)) * 3 + (T3);                                 \
      int lanep = l31 + 32 * (rq & 1);                                          \
      *(u32x2*)(smem + HS_OFF + ent * 1024 + lanep * 16 + hi * 8) = p;          \
    }                                                                           \
  }
    GELU_STORE(z0, 0)
    GELU_STORE(z1, 1)
    GELU_STORE(z2, 2)
    __syncthreads();
    // ---- GEMM2: ctiles w*2 + {0,1}, K = strip 256 (16 k-entries) ----
    const unsigned short* w2a =
        W2Pk + (size_t)e * dstE2 + ((size_t)(w * 2) * 128 + it * 16) * 512 + l * 8;
    const unsigned short* w2b = w2a + (size_t)128 * 512;
#pragma unroll 8
    for (int fs = 0; fs < 16; ++fs) {
      bf16x8 a0 = *(const bf16x8*)(w2a + (size_t)fs * 512);
      bf16x8 a1 = *(const bf16x8*)(w2b + (size_t)fs * 512);
      bf16x8 h0 = ld_frag(smem + HS_OFF + (fs * 3 + 0) * 1024 + l * 16);
      bf16x8 h1 = ld_frag(smem + HS_OFF + (fs * 3 + 1) * 1024 + l * 16);
      bf16x8 h2 = ld_frag(smem + HS_OFF + (fs * 3 + 2) * 1024 + l * 16);
      acc00 = __builtin_amdgcn_mfma_f32_32x32x16_bf16(a0, h0, acc00, 0, 0, 0);
      acc01 = __builtin_amdgcn_mfma_f32_32x32x16_bf16(a0, h1, acc01, 0, 0, 0);
      acc02 = __builtin_amdgcn_mfma_f32_32x32x16_bf16(a0, h2, acc02, 0, 0, 0);
      acc10 = __builtin_amdgcn_mfma_f32_32x32x16_bf16(a1, h0, acc10, 0, 0, 0);
      acc11 = __builtin_amdgcn_mfma_f32_32x32x16_bf16(a1, h1, acc11, 0, 0, 0);
      acc12 = __builtin_amdgcn_mfma_f32_32x32x16_bf16(a1, h2, acc12, 0, 0, 0);
    }
    __syncthreads();
  }
  // epilogue: (acc + b2) * wt -> bf16 -> LDS bounce (Xs area) [tok][c]
#define EPI_STORE(ACC, JC, T3)                                                  \
  {                                                                             \
    _Pragma("unroll") for (int rq = 0; rq < 4; ++rq) {                          \
      int c0 = (w * 2 + (JC)) * 32 + 8 * rq + 4 * hi;                           \
      float4 b2v = *(const float4*)(b2g + e * 512 + c0);                        \
      int tok = (T3)*32 + l31;                                                  \
      float wt = wts[tok];                                                      \
      u32x2 p;                                                                  \
      p.x = (unsigned)f2bf((ACC[4 * rq + 0] + b2v.x) * wt) |                    \
            ((unsigned)f2bf((ACC[4 * rq + 1] + b2v.y) * wt) << 16);             \
      p.y = (unsigned)f2bf((ACC[4 * rq + 2] + b2v.z) * wt) |                    \
            ((unsigned)f2bf((ACC[4 * rq + 3] + b2v.w) * wt) << 16);             \
      *(u32x2*)(smem + tok * 1024 + ((c0 * 2) ^ ((tok & 7) << 4))) = p;         \
    }                                                                           \
  }
  EPI_STORE(acc00, 0, 0)
  EPI_STORE(acc01, 0, 1)
  EPI_STORE(acc02, 0, 2)
  EPI_STORE(acc10, 1, 0)
  EPI_STORE(acc11, 1, 1)
  EPI_STORE(acc12, 1, 2)
  __syncthreads();
#pragma unroll
  for (int s = 0; s < 12; ++s) {
    int i = tid + s * 512;
    int row = i >> 6, g = i & 63;
    if (row < valid) {
      u32x4 v = *(u32x4*)(smem + row * 1024 + ((g * 16) ^ ((row & 7) << 4)));
      *(u32x4*)(Yb + (size_t)(base + row) * 512 + g * 8) = v;
    }
  }
}

// ---------------------------------------------------------------------------
// K8: head bf16 MFMA GEMM. M=8192, N=256, K=512. A[tok] = Yb[p1]+Yb[p2].
// ---------------------------------------------------------------------------
__global__ __launch_bounds__(256) void k_head(const unsigned short* __restrict__ Yb,
                                              const int* __restrict__ tokpos,
                                              const unsigned short* __restrict__ headPk,
                                              const float* __restrict__ headB,
                                              float* __restrict__ out) {
  __shared__ __align__(16) char As[16384];
  __shared__ int tp[256];
  int tid = threadIdx.x;
  int w = tid >> 6, l = tid & 63;
  int l31 = l & 31, hi = l >> 5;
  int mg = w & 1, ng = w >> 1;
  int bm = blockIdx.x * 128, by = blockIdx.y;
  tp[tid] = tokpos[bm * 2 + tid];
  f32x16 acc00, acc01, acc10, acc11;
#pragma unroll
  for (int i = 0; i < 16; ++i) { acc00[i] = 0.f; acc01[i] = 0.f; acc10[i] = 0.f; acc11[i] = 0.f; }
  int nblk0 = by * 4 + ng * 2;
  __syncthreads();
  for (int kb = 0; kb < 8; ++kb) {
#pragma unroll
    for (int s = 0; s < 4; ++s) {
      int i = tid + s * 256;
      int row = i >> 3, g = i & 7;
      int p1 = tp[row * 2], p2 = tp[row * 2 + 1];
      u32x4 va = *(const u32x4*)(Yb + (size_t)p1 * 512 + kb * 64 + g * 8);
      u32x4 vb = *(const u32x4*)(Yb + (size_t)p2 * 512 + kb * 64 + g * 8);
      u32x4 o;
      o.x = (unsigned)f2bf(bflo(va.x) + bflo(vb.x)) | ((unsigned)f2bf(bfhi(va.x) + bfhi(vb.x)) << 16);
      o.y = (unsigned)f2bf(bflo(va.y) + bflo(vb.y)) | ((unsigned)f2bf(bfhi(va.y) + bfhi(vb.y)) << 16);
      o.z = (unsigned)f2bf(bflo(va.z) + bflo(vb.z)) | ((unsigned)f2bf(bfhi(va.z) + bfhi(vb.z)) << 16);
      o.w = (unsigned)f2bf(bflo(va.w) + bflo(vb.w)) | ((unsigned)f2bf(bfhi(va.w) + bfhi(vb.w)) << 16);
      *(u32x4*)(As + row * 128 + ((g * 16) ^ ((row & 7) << 4))) = o;
    }
    __syncthreads();
#pragma unroll
    for (int ks = 0; ks < 4; ++ks) {
      int r0 = mg * 64 + l31, r1 = r0 + 32;
      int kbyte = ks * 32 + hi * 16;
      bf16x8 a0 = ld_frag(As + r0 * 128 + (kbyte ^ ((r0 & 7) << 4)));
      bf16x8 a1 = ld_frag(As + r1 * 128 + (kbyte ^ ((r1 & 7) << 4)));
      const unsigned short* hp = headPk + ((size_t)nblk0 * 32 + kb * 4 + ks) * 512 + l * 8;
      bf16x8 b0 = *(const bf16x8*)hp;
      bf16x8 b1 = *(const bf16x8*)(hp + 32 * 512);
      acc00 = __builtin_amdgcn_mfma_f32_32x32x16_bf16(a0, b0, acc00, 0, 0, 0);
      acc01 = __builtin_amdgcn_mfma_f32_32x32x16_bf16(a0, b1, acc01, 0, 0, 0);
      acc10 = __builtin_amdgcn_mfma_f32_32x32x16_bf16(a1, b0, acc10, 0, 0, 0);
      acc11 = __builtin_amdgcn_mfma_f32_32x32x16_bf16(a1, b1, acc11, 0, 0, 0);
    }
    __syncthreads();
  }
#pragma unroll
  for (int mf = 0; mf < 2; ++mf) {
#pragma unroll
    for (int nf = 0; nf < 2; ++nf) {
      int nc = by * 128 + ng * 64 + nf * 32 + l31;
      float hb = headB[nc];
#pragma unroll
      for (int r = 0; r < 16; ++r) {
        int m = bm + mg * 64 + mf * 32 + (r & 3) + 8 * (r >> 2) + 4 * hi;
        float v;
        if (mf == 0) v = (nf == 0) ? acc00[r] : acc01[r];
        else         v = (nf == 0) ? acc10[r] : acc11[r];
        out[(size_t)m * 256 + nc] = v + hb;
      }
    }
  }
}

extern "C" void kernel_launch(void* const* d_in, const int* in_sizes, int n_in,
                              void* d_out, int out_size, void* d_ws, size_t ws_size,
                              hipStream_t stream) {
  (void)in_sizes; (void)n_in; (void)out_size; (void)ws_size;
  const int* seq     = (const int*)d_in[0];
  const float* emb   = (const float*)d_in[1];
  const float* phi_w = (const float*)d_in[2];
  const float* phi_b = (const float*)d_in[3];
  const float* amp_w = (const float*)d_in[4];
  const float* amp_b = (const float*)d_in[5];
  const float* gate_w = (const float*)d_in[6];
  const float* gate_b = (const float*)d_in[7];
  const float* w1 = (const float*)d_in[8];
  const float* b1 = (const float*)d_in[9];
  const float* w2 = (const float*)d_in[10];
  const float* b2 = (const float*)d_in[11];
  const float* head_w = (const float*)d_in[12];
  const float* head_b = (const float*)d_in[13];
  float* out = (float*)d_out;

  char* ws = (char*)d_ws;
  const size_t BUF = 16777216;
  float* X    = (float*)(ws);                         // Xhi|Xlo -> xmoe (in place)
  float* COSb = (float*)(ws + BUF);                   // cos -> Yb (bf16)
  float* SINb = (float*)(ws + 2 * BUF);               // sin -> W1Pk (bf16)
  float* SIGb = (float*)(ws + 3 * BUF);               // sig -> W2Pk (bf16)
  unsigned short* XhiP = (unsigned short*)X;          // 8MB
  unsigned short* XloP = XhiP + (size_t)8192 * 512;   // 8MB
  unsigned short* Yb   = (unsigned short*)COSb;
  unsigned short* W1Pk = (unsigned short*)SINb;
  unsigned short* W2Pk = (unsigned short*)SIGb;
  char* sm = ws + 4 * BUF;
  int*      e01p   = (int*)(sm);                      // 32KB
  unsigned* w01p   = (unsigned*)(sm + 32768);         // 32KB
  int*      list   = (int*)(sm + 65536);              // 64KB
  float*    wlist  = (float*)(sm + 131072);           // 64KB
  int*      tokpos = (int*)(sm + 196608);             // 64KB
  int*      counts = (int*)(sm + 262144);
  int*      eoff   = (int*)(sm + 262144 + 64);
  unsigned short* headPk = (unsigned short*)(sm + 266240);  // 256KB
  int*      tmap   = (int*)(sm + 266240 + 262144);          // 272 ints

  k_embed2<<<2048, 256, 0, stream>>>(seq, emb, XhiP, XloP);
  k_pack_b<<<dim3(8, 1, 1), 256, 0, stream>>>(head_w, 256, 0, headPk, 0, 32);
  k_phi<<<dim3(64, 8), 256, 0, stream>>>(XhiP, XloP, phi_w, phi_b, amp_w, amp_b,
                                         COSb, SINb, SIGb);
  k_scan<<<32, 256, 0, stream>>>(COSb, SINb, SIGb, X, out + 2097152);
  k_pack_b<<<dim3(64, 1, 8), 256, 0, stream>>>(w1, 2048, (size_t)512 * 2048, W1Pk,
                                               (size_t)64 * 32 * 512, 32);
  k_pack_b<<<dim3(16, 4, 8), 256, 0, stream>>>(w2, 512, (size_t)2048 * 512, W2Pk,
                                               (size_t)16 * 128 * 512, 128);
  k_gate<<<256, 256, 0, stream>>>(X, gate_w, gate_b, e01p, w01p);
  k_build<<<1, 256, 0, stream>>>(e01p, w01p, list, wlist, counts, eoff, tokpos, tmap);
  k_ffn<<<192, 512, 0, stream>>>(X, list, wlist, counts, eoff, tmap,
                                 W1Pk, b1, W2Pk, b2, Yb);
  k_head<<<dim3(64, 2), 256, 0, stream>>>(Yb, tokpos, headPk, head_b, out);
}